// Round 1
// baseline (656.984 us; speedup 1.0000x reference)
//
#include <hip/hip_runtime.h>
#include <hip/hip_bf16.h>
#include <math.h>

#define N_NODES 20000
#define F_INN 512
#define HH 64
#define NLAYERS 8
#define E_EDGES 640000
#define COUT 40

typedef __bf16 bf16x8 __attribute__((ext_vector_type(8)));
typedef float f32x4 __attribute__((ext_vector_type(4)));
typedef unsigned short us8 __attribute__((ext_vector_type(8)));

__device__ __forceinline__ unsigned short f2bf(float f) {
    unsigned int u = __builtin_bit_cast(unsigned int, f);
    u += 0x7FFFu + ((u >> 16) & 1u);   // RNE
    return (unsigned short)(u >> 16);
}
__device__ __forceinline__ float bf2f(unsigned short s) {
    unsigned int u = ((unsigned int)s) << 16;
    return __builtin_bit_cast(float, u);
}

// Swizzled-tile fragment load. Tile layout: [rows][64 k] bf16, row stride 128B
// = 8 16B slots; element (r,k) lives at r*64 + ((k>>3)^(r&7))*8 + (k&7).
// Fragment for mfma_f32_16x16x32_bf16: lane l -> row base+(l&15), k = ks*32+(l>>4)*8+e.
__device__ __forceinline__ us8 ldfrag(const unsigned short* tile, int row, int ks, int lane) {
    int slot = ks * 4 + (lane >> 4);
    int off = row * 64 + ((slot ^ (row & 7)) << 3);
    return *(const us8*)(tile + off);
}

__device__ __forceinline__ f32x4 mfma16(us8 a, us8 b, f32x4 c) {
    return __builtin_amdgcn_mfma_f32_16x16x32_bf16(
        __builtin_bit_cast(bf16x8, a), __builtin_bit_cast(bf16x8, b), c, 0, 0, 0);
}

// ---------------- CSR build ----------------
__global__ __launch_bounds__(256) void k_hist(const int* __restrict__ row, int* __restrict__ cnt) {
    int e = blockIdx.x * 256 + threadIdx.x;
    if (e < E_EDGES) atomicAdd(&cnt[row[e]], 1);
}

__global__ __launch_bounds__(1024) void k_scan(const int* __restrict__ cnt, int* __restrict__ row_start,
                                               int* __restrict__ cursor) {
    __shared__ int sd[1024];
    int t = threadIdx.x;
    int local[20];
    int s = 0;
    int base = t * 20;
#pragma unroll
    for (int i = 0; i < 20; i++) {
        int idx = base + i;
        int v = (idx < N_NODES) ? cnt[idx] : 0;
        local[i] = v; s += v;
    }
    sd[t] = s;
    __syncthreads();
    for (int d = 1; d < 1024; d <<= 1) {
        int v = (t >= d) ? sd[t - d] : 0;
        __syncthreads();
        sd[t] += v;
        __syncthreads();
    }
    int run = sd[t] - s;  // exclusive prefix
#pragma unroll
    for (int i = 0; i < 20; i++) {
        int idx = base + i;
        if (idx < N_NODES) { row_start[idx] = run; cursor[idx] = run; run += local[i]; }
    }
    if (t == 1023) row_start[N_NODES] = sd[1023];
}

__global__ __launch_bounds__(256) void k_scatter(const int* __restrict__ row, const int* __restrict__ col,
                                                 const float* __restrict__ ewin, int* __restrict__ cursor,
                                                 int* __restrict__ ecol, float* __restrict__ ew) {
    int e = blockIdx.x * 256 + threadIdx.x;
    if (e < E_EDGES) {
        int r = row[e];
        int p = atomicAdd(&cursor[r], 1);
        ecol[p] = col[e];
        ew[p] = ewin[e];
    }
}

// ---------------- weight pre-transpose/swizzle (bf16) ----------------
// W0t[f][k] (64 x 512), swizzled per 8-slot groups of its 64-slot rows.
__global__ __launch_bounds__(256) void k_w0t(const float* __restrict__ w0, unsigned short* __restrict__ w0t) {
    int idx = blockIdx.x * 256 + threadIdx.x;  // 32768
    if (idx < F_INN * HH) {
        int k = idx >> 6, f = idx & 63;
        w0t[f * 512 + (((k >> 3) ^ (f & 7)) << 3) + (k & 7)] = f2bf(w0[idx]);
    }
}
// Wt[c][i][j] = lin1_w[(i*64+j)*40 + c], swizzled [64 x 64] tiles per class.
__global__ __launch_bounds__(256) void k_wt(const float* __restrict__ w1, unsigned short* __restrict__ wt) {
    int idx = blockIdx.x * 256 + threadIdx.x;  // 163840
    if (idx < HH * HH * COUT) {
        int klin = idx / 40;
        int c = idx - klin * 40;
        int i = klin >> 6, j = klin & 63;
        wt[c * 4096 + i * 64 + (((j >> 3) ^ (i & 7)) << 3) + (j & 7)] = f2bf(w1[idx]);
    }
}

// ---------------- lin0: h0 = relu(x @ W0 + b0), MFMA bf16 ----------------
__global__ __launch_bounds__(256) void k_lin0(const float* __restrict__ x, const unsigned short* __restrict__ w0t,
                                              const float* __restrict__ b0, float* __restrict__ h0) {
    __shared__ __align__(16) unsigned short As[32 * 64];
    __shared__ __align__(16) unsigned short Bs[64 * 64];
    const int t = threadIdx.x;
    const int w = t >> 6, lane = t & 63;
    const int r0 = blockIdx.x * 32;
    const int rA = t >> 3, g = t & 7;
    f32x4 acc[2] = {};
    for (int kc = 0; kc < 8; kc++) {
        if (kc) __syncthreads();
        {   // stage A chunk [32 x 64] from x, fp32->bf16, swizzled
            const float* src = x + (size_t)(r0 + rA) * F_INN + kc * 64 + g * 8;
            float4 f0 = *(const float4*)src;
            float4 f1 = *(const float4*)(src + 4);
            us8 v;
            v[0] = f2bf(f0.x); v[1] = f2bf(f0.y); v[2] = f2bf(f0.z); v[3] = f2bf(f0.w);
            v[4] = f2bf(f1.x); v[5] = f2bf(f1.y); v[6] = f2bf(f1.z); v[7] = f2bf(f1.w);
            *(us8*)(As + rA * 64 + ((g ^ (rA & 7)) << 3)) = v;
        }
        {   // stage B chunk [64 x 64] (pre-swizzled source -> plain strided copy)
            const int4* bsrc = (const int4*)w0t;
            int4* bdst = (int4*)Bs;
#pragma unroll
            for (int i = 0; i < 2; i++) {
                int flat = t * 2 + i;
                int f = flat >> 3, u = flat & 7;
                bdst[f * 8 + u] = bsrc[f * 64 + kc * 8 + u];
            }
        }
        __syncthreads();
#pragma unroll
        for (int ks = 0; ks < 2; ks++) {
            us8 b = ldfrag(Bs, w * 16 + (lane & 15), ks, lane);
            us8 a0 = ldfrag(As, (lane & 15), ks, lane);
            us8 a1 = ldfrag(As, 16 + (lane & 15), ks, lane);
            acc[0] = mfma16(a0, b, acc[0]);
            acc[1] = mfma16(a1, b, acc[1]);
        }
    }
    const int colc = w * 16 + (lane & 15);
    float bias = b0[colc];
#pragma unroll
    for (int mf = 0; mf < 2; mf++) {
#pragma unroll
        for (int reg = 0; reg < 4; reg++) {
            int rowg = r0 + mf * 16 + ((lane >> 4) << 2) + reg;
            h0[(size_t)rowg * HH + colc] = fmaxf(acc[mf][reg] + bias, 0.f);
        }
    }
}

// ---------------- fused GCN2 layer: spmm + residual + matvec + relu ----------------
__global__ __launch_bounds__(256) void k_layer(const float* __restrict__ hp, const float* __restrict__ h0,
                                               float* __restrict__ hn, const float* __restrict__ W,
                                               const int* __restrict__ row_start, const int* __restrict__ ecol,
                                               const float* __restrict__ ew, float beta) {
    __shared__ float Wl[4096];
    int t = threadIdx.x;
#pragma unroll
    for (int i = 0; i < 16; i++) Wl[t + i * 256] = W[t + i * 256];
    __syncthreads();
    int w = t >> 6, lane = t & 63;
    for (int r = blockIdx.x * 4 + w; r < N_NODES; r += gridDim.x * 4) {
        int e0 = row_start[r], e1 = row_start[r + 1];
        float a0 = 0.f, a1 = 0.f;
        int e = e0;
        for (; e + 2 <= e1; e += 2) {
            int c0 = ecol[e], c1 = ecol[e + 1];
            float we0 = ew[e], we1 = ew[e + 1];
            a0 += we0 * hp[(size_t)c0 * HH + lane];
            a1 += we1 * hp[(size_t)c1 * HH + lane];
        }
        if (e < e1) a0 += ew[e] * hp[(size_t)ecol[e] * HH + lane];
        float outv = 0.9f * (a0 + a1) + 0.1f * h0[(size_t)r * HH + lane];
        float tmp = 0.f;
#pragma unroll 8
        for (int k = 0; k < 64; k++) {
            float s = __builtin_bit_cast(float,
                __builtin_amdgcn_readlane(__builtin_bit_cast(int, outv), k));
            tmp += s * Wl[k * 64 + lane];
        }
        hn[(size_t)r * HH + lane] = fmaxf((1.f - beta) * outv + beta * tmp, 0.f);
    }
}

// ---------------- final quadratic form: q[n,c] = h^T M_c h via MFMA ----------------
__global__ __launch_bounds__(256) void k_qform(const float* __restrict__ h, const unsigned short* __restrict__ wt,
                                               float* __restrict__ q) {
    __shared__ __align__(16) unsigned short As[32 * 64];
    __shared__ __align__(16) unsigned short Bs[4 * 64 * 64];
    int t = threadIdx.x;
    int w = t >> 6, lane = t & 63;
    int r0 = blockIdx.x * 32;
    int cbase = blockIdx.y * 4;
    {   // stage A: h tile [32 x 64] fp32->bf16 swizzled
        int rA = t >> 3, g = t & 7;
        const float* src = h + (size_t)(r0 + rA) * HH + g * 8;
        float4 f0 = *(const float4*)src;
        float4 f1 = *(const float4*)(src + 4);
        us8 v;
        v[0] = f2bf(f0.x); v[1] = f2bf(f0.y); v[2] = f2bf(f0.z); v[3] = f2bf(f0.w);
        v[4] = f2bf(f1.x); v[5] = f2bf(f1.y); v[6] = f2bf(f1.z); v[7] = f2bf(f1.w);
        *(us8*)(As + rA * 64 + ((g ^ (rA & 7)) << 3)) = v;
    }
    {   // stage B: this wave's class tile (pre-swizzled) -> plain copy
        const int4* bsrc = (const int4*)(wt + (size_t)(cbase + w) * 4096);
        int4* bdst = (int4*)(Bs + w * 4096);
#pragma unroll
        for (int i = 0; i < 8; i++) bdst[i * 64 + lane] = bsrc[i * 64 + lane];
    }
    __syncthreads();
    f32x4 acc[2][4] = {};
#pragma unroll
    for (int ks = 0; ks < 2; ks++) {
        us8 a0 = ldfrag(As, (lane & 15), ks, lane);
        us8 a1 = ldfrag(As, 16 + (lane & 15), ks, lane);
#pragma unroll
        for (int nf = 0; nf < 4; nf++) {
            us8 b = ldfrag(Bs + w * 4096, nf * 16 + (lane & 15), ks, lane);
            acc[0][nf] = mfma16(a0, b, acc[0][nf]);
            acc[1][nf] = mfma16(a1, b, acc[1][nf]);
        }
    }
    // epilogue: q[row] = sum_i h[row,i] * G[row,i]; C layout col=lane&15, row=(lane>>4)*4+reg
#pragma unroll
    for (int mf = 0; mf < 2; mf++) {
#pragma unroll
        for (int reg = 0; reg < 4; reg++) {
            int rt = mf * 16 + ((lane >> 4) << 2) + reg;
            float v = 0.f;
#pragma unroll
            for (int nf = 0; nf < 4; nf++) {
                int k = nf * 16 + (lane & 15);
                float hb = bf2f(As[rt * 64 + (((k >> 3) ^ (rt & 7)) << 3) + (k & 7)]);
                v += acc[mf][nf][reg] * hb;
            }
            v += __shfl_xor(v, 1);
            v += __shfl_xor(v, 2);
            v += __shfl_xor(v, 4);
            v += __shfl_xor(v, 8);
            if ((lane & 15) == 0) q[(size_t)(r0 + rt) * COUT + cbase + w] = v;
        }
    }
}

// ---------------- finalize: gamma scale, lin1_b, expmap0, proj, log_softmax ----------------
__global__ __launch_bounds__(256) void k_final(const float* __restrict__ h, const float* __restrict__ q,
                                               const float* __restrict__ b1, float* __restrict__ out) {
    int t = threadIdx.x;
    int w = t >> 6, lane = t & 63;
    int r = blockIdx.x * 4 + w;
    float hv = h[(size_t)r * HH + lane];
    float s = hv * hv;
#pragma unroll
    for (int o = 1; o < 64; o <<= 1) s += __shfl_xor(s, o);
    // ||o||_F = ||h||^2 = s
    const float maxn = 1.0f - 4e-3f;
    float scale1 = (s > maxn) ? (maxn / s) : 1.f;
    float pn = fmaxf(s * scale1, 1e-15f);
    float tt = atanhf(fminf(pn, 1.f - 1e-7f));
    float gam = (tt / pn) * scale1;
    float z = 0.f;
    if (lane < COUT) z = gam * q[(size_t)r * COUT + lane] + b1[lane];
    float un2 = z * z;
#pragma unroll
    for (int o = 1; o < 64; o <<= 1) un2 += __shfl_xor(un2, o);
    float un = fmaxf(sqrtf(un2), 1e-15f);
    float th = tanhf(un);
    float fac = fminf(th, maxn) / un;
    float f = z * fac;
    float m = (lane < COUT) ? f : -1e30f;
#pragma unroll
    for (int o = 1; o < 64; o <<= 1) m = fmaxf(m, __shfl_xor(m, o));
    float ex = (lane < COUT) ? __expf(f - m) : 0.f;
    float se = ex;
#pragma unroll
    for (int o = 1; o < 64; o <<= 1) se += __shfl_xor(se, o);
    if (lane < COUT) out[(size_t)r * COUT + lane] = f - m - logf(se);
}

extern "C" void kernel_launch(void* const* d_in, const int* in_sizes, int n_in,
                              void* d_out, int out_size, void* d_ws, size_t ws_size,
                              hipStream_t stream) {
    (void)in_sizes; (void)n_in; (void)out_size; (void)ws_size;
    const float* x = (const float*)d_in[0];
    const int* row = (const int*)d_in[1];
    const int* col = (const int*)d_in[2];
    const float* eww = (const float*)d_in[3];
    const float* w0 = (const float*)d_in[4];
    const float* b0 = (const float*)d_in[5];
    const float* convw = (const float*)d_in[6];
    const float* w1 = (const float*)d_in[7];
    const float* b1 = (const float*)d_in[8];
    float* out = (float*)d_out;

    char* ws = (char*)d_ws;
    float* h0 = (float*)(ws + 0);                       // 5,120,000
    float* hA = (float*)(ws + 5120000);                 // 5,120,000
    float* hB = (float*)(ws + 10240000);                // 5,120,000
    float* q  = (float*)(ws + 15360000);                // 3,200,000
    int* rs   = (int*)(ws + 18560000);                  // 80,004 (padded 80,128)
    int* cur  = (int*)(ws + 18640128);                  // 80,000 (padded 80,128)
    int* ecol = (int*)(ws + 18720256);                  // 2,560,000
    float* ewS = (float*)(ws + 21280256);               // 2,560,000
    unsigned short* w0t = (unsigned short*)(ws + 23840256);  // 65,536
    unsigned short* wt  = (unsigned short*)(ws + 23905792);  // 327,680  (end ~24.2 MB)

    hipMemsetAsync(cur, 0, N_NODES * sizeof(int), stream);
    k_hist<<<2500, 256, 0, stream>>>(row, cur);
    k_scan<<<1, 1024, 0, stream>>>(cur, rs, cur);
    k_scatter<<<2500, 256, 0, stream>>>(row, col, eww, cur, ecol, ewS);
    k_w0t<<<128, 256, 0, stream>>>(w0, w0t);
    k_wt<<<640, 256, 0, stream>>>(w1, wt);
    k_lin0<<<625, 256, 0, stream>>>(x, w0t, b0, h0);

    const float* hp = h0;
    float* hn = hA;
    for (int l = 0; l < NLAYERS; l++) {
        float beta = logf(0.5f / (float)(l + 1) + 1.0f);
        k_layer<<<1250, 256, 0, stream>>>(hp, h0, hn, convw + (size_t)l * 4096, rs, ecol, ewS, beta);
        hp = hn;
        hn = (hn == hA) ? hB : hA;
    }
    // after 8 layers, hp points at the final h
    k_qform<<<dim3(625, 10), 256, 0, stream>>>(hp, wt, q);
    k_final<<<5000, 256, 0, stream>>>(hp, q, b1, out);
}

// Round 2
// 455.672 us; speedup vs baseline: 1.4418x; 1.4418x over previous
//
#include <hip/hip_runtime.h>
#include <hip/hip_bf16.h>
#include <math.h>

#define N_NODES 20000
#define F_INN 512
#define HH 64
#define NLAYERS 8
#define E_EDGES 640000
#define COUT 40
#define ECAP 800016   // padded CSR capacity: E + 8*N + slack

typedef __bf16 bf16x8 __attribute__((ext_vector_type(8)));
typedef float f32x4 __attribute__((ext_vector_type(4)));
typedef unsigned short us8 __attribute__((ext_vector_type(8)));

__device__ __forceinline__ unsigned short f2bf(float f) {
    unsigned int u = __builtin_bit_cast(unsigned int, f);
    u += 0x7FFFu + ((u >> 16) & 1u);   // RNE
    return (unsigned short)(u >> 16);
}
__device__ __forceinline__ float bf2f(unsigned short s) {
    unsigned int u = ((unsigned int)s) << 16;
    return __builtin_bit_cast(float, u);
}

// Swizzled-tile fragment load. Tile layout: [rows][64 k] bf16, row stride 128B
// = 8 16B slots; element (r,k) lives at r*64 + ((k>>3)^(r&7))*8 + (k&7).
// Fragment for mfma_f32_16x16x32_bf16: lane l -> row base+(l&15), k = ks*32+(l>>4)*8+e.
__device__ __forceinline__ us8 ldfrag(const unsigned short* tile, int row, int ks, int lane) {
    int slot = ks * 4 + (lane >> 4);
    int off = row * 64 + ((slot ^ (row & 7)) << 3);
    return *(const us8*)(tile + off);
}

__device__ __forceinline__ f32x4 mfma16(us8 a, us8 b, f32x4 c) {
    return __builtin_amdgcn_mfma_f32_16x16x32_bf16(
        __builtin_bit_cast(bf16x8, a), __builtin_bit_cast(bf16x8, b), c, 0, 0, 0);
}

// ---------------- CSR build ----------------
__global__ __launch_bounds__(256) void k_hist(const int* __restrict__ row, int* __restrict__ cnt) {
    int e = blockIdx.x * 256 + threadIdx.x;
    if (e < E_EDGES) atomicAdd(&cnt[row[e]], 1);
}

// prefix-scan with per-row padding to multiple of 8 (so spmm can read aligned
// int4/float4 groups with no tail handling; pad slots are zero-weight edges).
__global__ __launch_bounds__(1024) void k_scan(const int* __restrict__ cnt, int* __restrict__ row_start,
                                               int* __restrict__ cursor) {
    __shared__ int sd[1024];
    int t = threadIdx.x;
    int local[20];
    int s = 0;
    int base = t * 20;
#pragma unroll
    for (int i = 0; i < 20; i++) {
        int idx = base + i;
        int v = (idx < N_NODES) ? ((cnt[idx] + 7) & ~7) : 0;
        local[i] = v; s += v;
    }
    sd[t] = s;
    __syncthreads();
    for (int d = 1; d < 1024; d <<= 1) {
        int v = (t >= d) ? sd[t - d] : 0;
        __syncthreads();
        sd[t] += v;
        __syncthreads();
    }
    int run = sd[t] - s;  // exclusive prefix
#pragma unroll
    for (int i = 0; i < 20; i++) {
        int idx = base + i;
        if (idx < N_NODES) { row_start[idx] = run; cursor[idx] = run; run += local[i]; }
    }
    if (t == 1023) row_start[N_NODES] = sd[1023];
}

__global__ __launch_bounds__(256) void k_scatter(const int* __restrict__ row, const int* __restrict__ col,
                                                 const float* __restrict__ ewin, int* __restrict__ cursor,
                                                 int* __restrict__ ecol, float* __restrict__ ew) {
    int e = blockIdx.x * 256 + threadIdx.x;
    if (e < E_EDGES) {
        int r = row[e];
        int p = atomicAdd(&cursor[r], 1);
        ecol[p] = col[e];
        ew[p] = ewin[e];
    }
}

// ---------------- weight pre-transpose/swizzle (bf16) ----------------
__global__ __launch_bounds__(256) void k_w0t(const float* __restrict__ w0, unsigned short* __restrict__ w0t) {
    int idx = blockIdx.x * 256 + threadIdx.x;  // 32768
    if (idx < F_INN * HH) {
        int k = idx >> 6, f = idx & 63;
        w0t[f * 512 + (((k >> 3) ^ (f & 7)) << 3) + (k & 7)] = f2bf(w0[idx]);
    }
}
__global__ __launch_bounds__(256) void k_wt(const float* __restrict__ w1, unsigned short* __restrict__ wt) {
    int idx = blockIdx.x * 256 + threadIdx.x;  // 163840
    if (idx < HH * HH * COUT) {
        int klin = idx / 40;
        int c = idx - klin * 40;
        int i = klin >> 6, j = klin & 63;
        wt[c * 4096 + i * 64 + (((j >> 3) ^ (i & 7)) << 3) + (j & 7)] = f2bf(w1[idx]);
    }
}

// W'[l] = (1-beta_l) I + beta_l conv_w[l]; stored transposed [c][k], hi/lo bf16, swizzled.
__global__ __launch_bounds__(256) void k_wprep(const float* __restrict__ convw,
                                               unsigned short* __restrict__ WH, unsigned short* __restrict__ WL) {
    int idx = blockIdx.x * 256 + threadIdx.x;  // 8*4096
    if (idx < NLAYERS * HH * HH) {
        int l = idx >> 12;
        int r12 = idx & 4095;
        int c = r12 >> 6, k = r12 & 63;
        float beta = logf(0.5f / (float)(l + 1) + 1.0f);
        float v = beta * convw[l * 4096 + k * 64 + c] + ((k == c) ? (1.0f - beta) : 0.0f);
        unsigned short hi = f2bf(v);
        unsigned short lo = f2bf(v - bf2f(hi));
        int off = l * 4096 + c * 64 + (((k >> 3) ^ (c & 7)) << 3) + (k & 7);
        WH[off] = hi;
        WL[off] = lo;
    }
}

// ---------------- lin0: h0 = relu(x @ W0 + b0), MFMA bf16 ----------------
__global__ __launch_bounds__(256) void k_lin0(const float* __restrict__ x, const unsigned short* __restrict__ w0t,
                                              const float* __restrict__ b0, float* __restrict__ h0) {
    __shared__ __align__(16) unsigned short As[32 * 64];
    __shared__ __align__(16) unsigned short Bs[64 * 64];
    const int t = threadIdx.x;
    const int w = t >> 6, lane = t & 63;
    const int r0 = blockIdx.x * 32;
    const int rA = t >> 3, g = t & 7;
    f32x4 acc[2] = {};
    for (int kc = 0; kc < 8; kc++) {
        if (kc) __syncthreads();
        {
            const float* src = x + (size_t)(r0 + rA) * F_INN + kc * 64 + g * 8;
            float4 f0 = *(const float4*)src;
            float4 f1 = *(const float4*)(src + 4);
            us8 v;
            v[0] = f2bf(f0.x); v[1] = f2bf(f0.y); v[2] = f2bf(f0.z); v[3] = f2bf(f0.w);
            v[4] = f2bf(f1.x); v[5] = f2bf(f1.y); v[6] = f2bf(f1.z); v[7] = f2bf(f1.w);
            *(us8*)(As + rA * 64 + ((g ^ (rA & 7)) << 3)) = v;
        }
        {
            const int4* bsrc = (const int4*)w0t;
            int4* bdst = (int4*)Bs;
#pragma unroll
            for (int i = 0; i < 2; i++) {
                int flat = t * 2 + i;
                int f = flat >> 3, u = flat & 7;
                bdst[f * 8 + u] = bsrc[f * 64 + kc * 8 + u];
            }
        }
        __syncthreads();
#pragma unroll
        for (int ks = 0; ks < 2; ks++) {
            us8 b = ldfrag(Bs, w * 16 + (lane & 15), ks, lane);
            us8 a0 = ldfrag(As, (lane & 15), ks, lane);
            us8 a1 = ldfrag(As, 16 + (lane & 15), ks, lane);
            acc[0] = mfma16(a0, b, acc[0]);
            acc[1] = mfma16(a1, b, acc[1]);
        }
    }
    const int colc = w * 16 + (lane & 15);
    float bias = b0[colc];
#pragma unroll
    for (int mf = 0; mf < 2; mf++) {
#pragma unroll
        for (int reg = 0; reg < 4; reg++) {
            int rowg = r0 + mf * 16 + ((lane >> 4) << 2) + reg;
            h0[(size_t)rowg * HH + colc] = fmaxf(acc[mf][reg] + bias, 0.f);
        }
    }
}

// ---------------- spmm: out = 0.9*(A @ hp) + 0.1*h0, packed hi/lo bf16 ----------------
__global__ __launch_bounds__(256) void k_spmm(const float* __restrict__ hp, const float* __restrict__ h0,
                                              unsigned int* __restrict__ outP,
                                              const int* __restrict__ row_start, const int* __restrict__ ecol,
                                              const float* __restrict__ ew) {
    const int wid = blockIdx.x * 4 + (threadIdx.x >> 6);  // one wave per row, grid 5000
    const int lane = threadIdx.x & 63;
    const int e0 = row_start[wid], e1 = row_start[wid + 1];
    float acc = 0.f;
    for (int e = e0; e < e1; e += 8) {
        int4 c0 = *(const int4*)(ecol + e);
        int4 c1 = *(const int4*)(ecol + e + 4);
        float4 w0 = *(const float4*)(ew + e);
        float4 w1 = *(const float4*)(ew + e + 4);
        acc += w0.x * hp[(size_t)c0.x * HH + lane];
        acc += w0.y * hp[(size_t)c0.y * HH + lane];
        acc += w0.z * hp[(size_t)c0.z * HH + lane];
        acc += w0.w * hp[(size_t)c0.w * HH + lane];
        acc += w1.x * hp[(size_t)c1.x * HH + lane];
        acc += w1.y * hp[(size_t)c1.y * HH + lane];
        acc += w1.z * hp[(size_t)c1.z * HH + lane];
        acc += w1.w * hp[(size_t)c1.w * HH + lane];
    }
    float outv = 0.9f * acc + 0.1f * h0[(size_t)wid * HH + lane];
    unsigned short hi = f2bf(outv);
    unsigned short lo = f2bf(outv - bf2f(hi));
    outP[(size_t)wid * HH + lane] = ((unsigned int)hi << 16) | lo;
}

// ---------------- layer GEMM: h = relu(out @ W'), split-bf16 MFMA ----------------
__global__ __launch_bounds__(256) void k_gemm_layer(const unsigned int* __restrict__ outP,
                                                    const unsigned short* __restrict__ WHg,
                                                    const unsigned short* __restrict__ WLg,
                                                    float* __restrict__ hn) {
    __shared__ __align__(16) unsigned short AHi[64 * 64];
    __shared__ __align__(16) unsigned short ALo[64 * 64];
    __shared__ __align__(16) unsigned short WHs[64 * 64];
    __shared__ __align__(16) unsigned short WLs[64 * 64];
    const int t = threadIdx.x;
    const int w = t >> 6, lane = t & 63;
    const int r0 = blockIdx.x * 64;
    {   // stage W' hi/lo (pre-swizzled): 512 int4 each, 2 per thread
        const int4* sh = (const int4*)WHg;
        const int4* sl = (const int4*)WLg;
        int4* dh = (int4*)WHs;
        int4* dl = (int4*)WLs;
        dh[t] = sh[t]; dh[t + 256] = sh[t + 256];
        dl[t] = sl[t]; dl[t + 256] = sl[t + 256];
    }
    {   // stage A: unpack packed hi/lo, swizzle
#pragma unroll
        for (int it = 0; it < 2; it++) {
            int flat = t + it * 256;         // 0..511
            int rA = flat >> 3, g = flat & 7;
            const uint4* src = (const uint4*)(outP + (size_t)(r0 + rA) * HH + g * 8);
            uint4 u0 = src[0], u1 = src[1];
            us8 hi, lo;
            hi[0] = u0.x >> 16; lo[0] = u0.x & 0xFFFF;
            hi[1] = u0.y >> 16; lo[1] = u0.y & 0xFFFF;
            hi[2] = u0.z >> 16; lo[2] = u0.z & 0xFFFF;
            hi[3] = u0.w >> 16; lo[3] = u0.w & 0xFFFF;
            hi[4] = u1.x >> 16; lo[4] = u1.x & 0xFFFF;
            hi[5] = u1.y >> 16; lo[5] = u1.y & 0xFFFF;
            hi[6] = u1.z >> 16; lo[6] = u1.z & 0xFFFF;
            hi[7] = u1.w >> 16; lo[7] = u1.w & 0xFFFF;
            int off = rA * 64 + ((g ^ (rA & 7)) << 3);
            *(us8*)(AHi + off) = hi;
            *(us8*)(ALo + off) = lo;
        }
    }
    __syncthreads();
    f32x4 acc[4] = {};
#pragma unroll
    for (int ks = 0; ks < 2; ks++) {
        us8 aH = ldfrag(AHi, w * 16 + (lane & 15), ks, lane);
        us8 aL = ldfrag(ALo, w * 16 + (lane & 15), ks, lane);
#pragma unroll
        for (int nf = 0; nf < 4; nf++) {
            us8 bH = ldfrag(WHs, nf * 16 + (lane & 15), ks, lane);
            us8 bL = ldfrag(WLs, nf * 16 + (lane & 15), ks, lane);
            acc[nf] = mfma16(aH, bH, acc[nf]);
            acc[nf] = mfma16(aH, bL, acc[nf]);
            acc[nf] = mfma16(aL, bH, acc[nf]);
        }
    }
#pragma unroll
    for (int nf = 0; nf < 4; nf++) {
#pragma unroll
        for (int reg = 0; reg < 4; reg++) {
            int rowg = r0 + w * 16 + ((lane >> 4) << 2) + reg;
            if (rowg < N_NODES)
                hn[(size_t)rowg * HH + nf * 16 + (lane & 15)] = fmaxf(acc[nf][reg], 0.f);
        }
    }
}

// ---------------- final quadratic form: q[n,c] = h^T M_c h via MFMA ----------------
__global__ __launch_bounds__(256) void k_qform(const float* __restrict__ h, const unsigned short* __restrict__ wt,
                                               float* __restrict__ q) {
    __shared__ __align__(16) unsigned short As[32 * 64];
    __shared__ __align__(16) unsigned short Bs[4 * 64 * 64];
    int t = threadIdx.x;
    int w = t >> 6, lane = t & 63;
    int r0 = blockIdx.x * 32;
    int cbase = blockIdx.y * 4;
    {
        int rA = t >> 3, g = t & 7;
        const float* src = h + (size_t)(r0 + rA) * HH + g * 8;
        float4 f0 = *(const float4*)src;
        float4 f1 = *(const float4*)(src + 4);
        us8 v;
        v[0] = f2bf(f0.x); v[1] = f2bf(f0.y); v[2] = f2bf(f0.z); v[3] = f2bf(f0.w);
        v[4] = f2bf(f1.x); v[5] = f2bf(f1.y); v[6] = f2bf(f1.z); v[7] = f2bf(f1.w);
        *(us8*)(As + rA * 64 + ((g ^ (rA & 7)) << 3)) = v;
    }
    {
        const int4* bsrc = (const int4*)(wt + (size_t)(cbase + w) * 4096);
        int4* bdst = (int4*)(Bs + w * 4096);
#pragma unroll
        for (int i = 0; i < 8; i++) bdst[i * 64 + lane] = bsrc[i * 64 + lane];
    }
    __syncthreads();
    f32x4 acc[2][4] = {};
#pragma unroll
    for (int ks = 0; ks < 2; ks++) {
        us8 a0 = ldfrag(As, (lane & 15), ks, lane);
        us8 a1 = ldfrag(As, 16 + (lane & 15), ks, lane);
#pragma unroll
        for (int nf = 0; nf < 4; nf++) {
            us8 b = ldfrag(Bs + w * 4096, nf * 16 + (lane & 15), ks, lane);
            acc[0][nf] = mfma16(a0, b, acc[0][nf]);
            acc[1][nf] = mfma16(a1, b, acc[1][nf]);
        }
    }
#pragma unroll
    for (int mf = 0; mf < 2; mf++) {
#pragma unroll
        for (int reg = 0; reg < 4; reg++) {
            int rt = mf * 16 + ((lane >> 4) << 2) + reg;
            float v = 0.f;
#pragma unroll
            for (int nf = 0; nf < 4; nf++) {
                int k = nf * 16 + (lane & 15);
                float hb = bf2f(As[rt * 64 + (((k >> 3) ^ (rt & 7)) << 3) + (k & 7)]);
                v += acc[mf][nf][reg] * hb;
            }
            v += __shfl_xor(v, 1);
            v += __shfl_xor(v, 2);
            v += __shfl_xor(v, 4);
            v += __shfl_xor(v, 8);
            if ((lane & 15) == 0) q[(size_t)(r0 + rt) * COUT + cbase + w] = v;
        }
    }
}

// ---------------- finalize ----------------
__global__ __launch_bounds__(256) void k_final(const float* __restrict__ h, const float* __restrict__ q,
                                               const float* __restrict__ b1, float* __restrict__ out) {
    int t = threadIdx.x;
    int w = t >> 6, lane = t & 63;
    int r = blockIdx.x * 4 + w;
    float hv = h[(size_t)r * HH + lane];
    float s = hv * hv;
#pragma unroll
    for (int o = 1; o < 64; o <<= 1) s += __shfl_xor(s, o);
    const float maxn = 1.0f - 4e-3f;
    float scale1 = (s > maxn) ? (maxn / s) : 1.f;
    float pn = fmaxf(s * scale1, 1e-15f);
    float tt = atanhf(fminf(pn, 1.f - 1e-7f));
    float gam = (tt / pn) * scale1;
    float z = 0.f;
    if (lane < COUT) z = gam * q[(size_t)r * COUT + lane] + b1[lane];
    float un2 = z * z;
#pragma unroll
    for (int o = 1; o < 64; o <<= 1) un2 += __shfl_xor(un2, o);
    float un = fmaxf(sqrtf(un2), 1e-15f);
    float th = tanhf(un);
    float fac = fminf(th, maxn) / un;
    float f = z * fac;
    float m = (lane < COUT) ? f : -1e30f;
#pragma unroll
    for (int o = 1; o < 64; o <<= 1) m = fmaxf(m, __shfl_xor(m, o));
    float ex = (lane < COUT) ? __expf(f - m) : 0.f;
    float se = ex;
#pragma unroll
    for (int o = 1; o < 64; o <<= 1) se += __shfl_xor(se, o);
    if (lane < COUT) out[(size_t)r * COUT + lane] = f - m - logf(se);
}

extern "C" void kernel_launch(void* const* d_in, const int* in_sizes, int n_in,
                              void* d_out, int out_size, void* d_ws, size_t ws_size,
                              hipStream_t stream) {
    (void)in_sizes; (void)n_in; (void)out_size; (void)ws_size;
    const float* x = (const float*)d_in[0];
    const int* row = (const int*)d_in[1];
    const int* col = (const int*)d_in[2];
    const float* eww = (const float*)d_in[3];
    const float* w0 = (const float*)d_in[4];
    const float* b0 = (const float*)d_in[5];
    const float* convw = (const float*)d_in[6];
    const float* w1 = (const float*)d_in[7];
    const float* b1 = (const float*)d_in[8];
    float* out = (float*)d_out;

    char* ws = (char*)d_ws;
    float* h0 = (float*)(ws + 0);                          // 5,120,000
    float* hA = (float*)(ws + 5120000);                    // 5,120,000
    float* hB = (float*)(ws + 10240000);                   // 5,120,000
    unsigned int* outP = (unsigned int*)(ws + 15360000);   // 20032*64*4 = 5,128,192
    float* q = (float*)(ws + 15360000);                    // alias outP (used after layers done)
    int* rs   = (int*)(ws + 20488192);                     // 80,004 -> pad 80,016
    int* cur  = (int*)(ws + 20568208);                     // 80,000
    int* ecol = (int*)(ws + 20648208);                     // ECAP*4 = 3,200,064
    float* ewS = (float*)(ws + 23848272);                  // 3,200,064
    unsigned short* w0t = (unsigned short*)(ws + 27048336);  // 65,536
    unsigned short* wt  = (unsigned short*)(ws + 27113872);  // 327,680
    unsigned short* WH  = (unsigned short*)(ws + 27441552);  // 65,536
    unsigned short* WL  = (unsigned short*)(ws + 27507088);  // 65,536 -> end ~27.6 MB

    hipMemsetAsync(cur, 0, N_NODES * sizeof(int), stream);
    hipMemsetAsync(ecol, 0, ECAP * sizeof(int), stream);
    hipMemsetAsync(ewS, 0, ECAP * sizeof(float), stream);
    k_hist<<<2500, 256, 0, stream>>>(row, cur);
    k_scan<<<1, 1024, 0, stream>>>(cur, rs, cur);
    k_scatter<<<2500, 256, 0, stream>>>(row, col, eww, cur, ecol, ewS);
    k_w0t<<<128, 256, 0, stream>>>(w0, w0t);
    k_wt<<<640, 256, 0, stream>>>(w1, wt);
    k_wprep<<<128, 256, 0, stream>>>(convw, WH, WL);
    k_lin0<<<625, 256, 0, stream>>>(x, w0t, b0, h0);

    const float* hp = h0;
    float* hn = hA;
    for (int l = 0; l < NLAYERS; l++) {
        k_spmm<<<5000, 256, 0, stream>>>(hp, h0, outP, rs, ecol, ewS);
        k_gemm_layer<<<313, 256, 0, stream>>>(outP, WH + l * 4096, WL + l * 4096, hn);
        hp = hn;
        hn = (hn == hA) ? hB : hA;
    }
    k_qform<<<dim3(625, 10), 256, 0, stream>>>(hp, wt, q);
    k_final<<<5000, 256, 0, stream>>>(hp, q, b1, out);
}

// Round 4
// 428.769 us; speedup vs baseline: 1.5323x; 1.0627x over previous
//
#include <hip/hip_runtime.h>
#include <hip/hip_bf16.h>
#include <math.h>

#define N_NODES 20000
#define F_INN 512
#define HH 64
#define NLAYERS 8
#define E_EDGES 640000
#define COUT 40
#define ECAP 800016   // padded CSR capacity: sum ceil(deg/8)*8 <= E + 7*N = 780000

typedef __bf16 bf16x8 __attribute__((ext_vector_type(8)));
typedef float f32x4 __attribute__((ext_vector_type(4)));
typedef unsigned short us8 __attribute__((ext_vector_type(8)));

__device__ __forceinline__ unsigned short f2bf(float f) {
    unsigned int u = __builtin_bit_cast(unsigned int, f);
    u += 0x7FFFu + ((u >> 16) & 1u);   // RNE
    return (unsigned short)(u >> 16);
}
__device__ __forceinline__ float bf2f(unsigned short s) {
    unsigned int u = ((unsigned int)s) << 16;
    return __builtin_bit_cast(float, u);
}
__device__ __forceinline__ float i2f(int s) { return __builtin_bit_cast(float, s); }

// Swizzled-tile fragment load (MFMA 16x16x32 bf16). Tile [rows][64k] bf16,
// element (r,k) at r*64 + ((k>>3)^(r&7))*8 + (k&7).
__device__ __forceinline__ us8 ldfrag(const unsigned short* tile, int row, int ks, int lane) {
    int slot = ks * 4 + (lane >> 4);
    int off = row * 64 + ((slot ^ (row & 7)) << 3);
    return *(const us8*)(tile + off);
}

__device__ __forceinline__ f32x4 mfma16(us8 a, us8 b, f32x4 c) {
    return __builtin_amdgcn_mfma_f32_16x16x32_bf16(
        __builtin_bit_cast(bf16x8, a), __builtin_bit_cast(bf16x8, b), c, 0, 0, 0);
}

// ---------------- CSR build ----------------
__global__ __launch_bounds__(256) void k_hist(const int* __restrict__ row, int* __restrict__ cnt) {
    int e = blockIdx.x * 256 + threadIdx.x;
    if (e < E_EDGES) atomicAdd(&cnt[row[e]], 1);
}

__global__ __launch_bounds__(1024) void k_scan(const int* __restrict__ cnt, int* __restrict__ row_start,
                                               int* __restrict__ cursor) {
    __shared__ int sd[1024];
    int t = threadIdx.x;
    int local[20];
    int s = 0;
    int base = t * 20;
#pragma unroll
    for (int i = 0; i < 20; i++) {
        int idx = base + i;
        int v = (idx < N_NODES) ? ((cnt[idx] + 7) & ~7) : 0;   // pad rows to x8
        local[i] = v; s += v;
    }
    sd[t] = s;
    __syncthreads();
    for (int d = 1; d < 1024; d <<= 1) {
        int v = (t >= d) ? sd[t - d] : 0;
        __syncthreads();
        sd[t] += v;
        __syncthreads();
    }
    int run = sd[t] - s;
#pragma unroll
    for (int i = 0; i < 20; i++) {
        int idx = base + i;
        if (idx < N_NODES) { row_start[idx] = run; cursor[idx] = run; run += local[i]; }
    }
    if (t == 1023) row_start[N_NODES] = sd[1023];
}

__global__ __launch_bounds__(256) void k_scatter(const int* __restrict__ row, const int* __restrict__ col,
                                                 const float* __restrict__ ewin, int* __restrict__ cursor,
                                                 int2* __restrict__ epk) {
    int e = blockIdx.x * 256 + threadIdx.x;
    if (e < E_EDGES) {
        int r = row[e];
        int p = atomicAdd(&cursor[r], 1);
        int2 v;
        v.x = col[e];
        v.y = __builtin_bit_cast(int, ewin[e]);
        epk[p] = v;
    }
}

// ---------------- weight prep ----------------
__global__ __launch_bounds__(256) void k_w0t(const float* __restrict__ w0, unsigned short* __restrict__ w0t) {
    int idx = blockIdx.x * 256 + threadIdx.x;  // 32768
    if (idx < F_INN * HH) {
        int k = idx >> 6, f = idx & 63;
        w0t[f * 512 + (((k >> 3) ^ (f & 7)) << 3) + (k & 7)] = f2bf(w0[idx]);
    }
}
__global__ __launch_bounds__(256) void k_wt(const float* __restrict__ w1, unsigned short* __restrict__ wt) {
    int idx = blockIdx.x * 256 + threadIdx.x;  // 163840
    if (idx < HH * HH * COUT) {
        int klin = idx / 40;
        int c = idx - klin * 40;
        int i = klin >> 6, j = klin & 63;
        wt[c * 4096 + i * 64 + (((j >> 3) ^ (i & 7)) << 3) + (j & 7)] = f2bf(w1[idx]);
    }
}
// Wf[l][k][c] = beta_l*conv_w[l][k][c] + (k==c)*(1-beta_l), f32 (no transpose)
__global__ __launch_bounds__(256) void k_wprep(const float* __restrict__ convw, float* __restrict__ Wf) {
    int idx = blockIdx.x * 256 + threadIdx.x;  // 8*4096
    if (idx < NLAYERS * HH * HH) {
        int l = idx >> 12;
        int k = (idx >> 6) & 63, c = idx & 63;
        float beta = logf(0.5f / (float)(l + 1) + 1.0f);
        Wf[idx] = beta * convw[idx] + ((k == c) ? (1.0f - beta) : 0.0f);
    }
}

// ---------------- lin0: h0 = relu(x @ W0 + b0), MFMA bf16 ----------------
__global__ __launch_bounds__(256) void k_lin0(const float* __restrict__ x, const unsigned short* __restrict__ w0t,
                                              const float* __restrict__ b0, float* __restrict__ h0) {
    __shared__ __align__(16) unsigned short As[32 * 64];
    __shared__ __align__(16) unsigned short Bs[64 * 64];
    const int t = threadIdx.x;
    const int w = t >> 6, lane = t & 63;
    const int r0 = blockIdx.x * 32;
    const int rA = t >> 3, g = t & 7;
    f32x4 acc[2] = {};
    for (int kc = 0; kc < 8; kc++) {
        if (kc) __syncthreads();
        {
            const float* src = x + (size_t)(r0 + rA) * F_INN + kc * 64 + g * 8;
            float4 f0 = *(const float4*)src;
            float4 f1 = *(const float4*)(src + 4);
            us8 v;
            v[0] = f2bf(f0.x); v[1] = f2bf(f0.y); v[2] = f2bf(f0.z); v[3] = f2bf(f0.w);
            v[4] = f2bf(f1.x); v[5] = f2bf(f1.y); v[6] = f2bf(f1.z); v[7] = f2bf(f1.w);
            *(us8*)(As + rA * 64 + ((g ^ (rA & 7)) << 3)) = v;
        }
        {
            const int4* bsrc = (const int4*)w0t;
            int4* bdst = (int4*)Bs;
#pragma unroll
            for (int i = 0; i < 2; i++) {
                int flat = t * 2 + i;
                int f = flat >> 3, u = flat & 7;
                bdst[f * 8 + u] = bsrc[f * 64 + kc * 8 + u];
            }
        }
        __syncthreads();
#pragma unroll
        for (int ks = 0; ks < 2; ks++) {
            us8 b = ldfrag(Bs, w * 16 + (lane & 15), ks, lane);
            us8 a0 = ldfrag(As, (lane & 15), ks, lane);
            us8 a1 = ldfrag(As, 16 + (lane & 15), ks, lane);
            acc[0] = mfma16(a0, b, acc[0]);
            acc[1] = mfma16(a1, b, acc[1]);
        }
    }
    const int colc = w * 16 + (lane & 15);
    float bias = b0[colc];
#pragma unroll
    for (int mf = 0; mf < 2; mf++) {
#pragma unroll
        for (int reg = 0; reg < 4; reg++) {
            int rowg = r0 + mf * 16 + ((lane >> 4) << 2) + reg;
            h0[(size_t)rowg * HH + colc] = fmaxf(acc[mf][reg] + bias, 0.f);
        }
    }
}

// ---------------- fused layer: gather-spmm + residual + matvec(W') + relu ----------------
__global__ __launch_bounds__(256) void k_layer(const float* __restrict__ hp, const float* __restrict__ h0,
                                               float* __restrict__ hn, const float* __restrict__ W,
                                               const int* __restrict__ rs, const int2* __restrict__ epk) {
    __shared__ float Wl[4096];
    __shared__ float rowbuf[4][64];
    const int t = threadIdx.x;
#pragma unroll
    for (int i = 0; i < 16; i++) Wl[t + i * 256] = W[t + i * 256];
    __syncthreads();
    const int w = t >> 6, lane = t & 63;
    const int r = blockIdx.x * 4 + w;
    const int e0 = rs[r], e1 = rs[r + 1];
    float acc = 0.f;
    int e = e0;
    if (e < e1) {
        int4 a = *(const int4*)(epk + e);
        int4 b = *(const int4*)(epk + e + 2);
        int4 c = *(const int4*)(epk + e + 4);
        int4 d = *(const int4*)(epk + e + 6);
        for (;;) {
            int4 A = a, B = b, C = c, D = d;
            int en = e + 8;
            bool more = en < e1;
            if (more) {
                a = *(const int4*)(epk + en);
                b = *(const int4*)(epk + en + 2);
                c = *(const int4*)(epk + en + 4);
                d = *(const int4*)(epk + en + 6);
            }
            acc += i2f(A.y) * hp[(size_t)A.x * HH + lane];
            acc += i2f(A.w) * hp[(size_t)A.z * HH + lane];
            acc += i2f(B.y) * hp[(size_t)B.x * HH + lane];
            acc += i2f(B.w) * hp[(size_t)B.z * HH + lane];
            acc += i2f(C.y) * hp[(size_t)C.x * HH + lane];
            acc += i2f(C.w) * hp[(size_t)C.z * HH + lane];
            acc += i2f(D.y) * hp[(size_t)D.x * HH + lane];
            acc += i2f(D.w) * hp[(size_t)D.z * HH + lane];
            if (!more) break;
            e = en;
        }
    }
    float outv = 0.9f * acc + 0.1f * h0[(size_t)r * HH + lane];
    rowbuf[w][lane] = outv;
    float tmp = 0.f;
    const float* rb = rowbuf[w];
#pragma unroll
    for (int k = 0; k < 64; k += 4) {
        float4 o = *(const float4*)(rb + k);
        tmp += o.x * Wl[(k + 0) * 64 + lane];
        tmp += o.y * Wl[(k + 1) * 64 + lane];
        tmp += o.z * Wl[(k + 2) * 64 + lane];
        tmp += o.w * Wl[(k + 3) * 64 + lane];
    }
    hn[(size_t)r * HH + lane] = fmaxf(tmp, 0.f);
}

// ---------------- final quadratic form: q[n,c] = h^T M_c h via MFMA ----------------
__global__ __launch_bounds__(256) void k_qform(const float* __restrict__ h, const unsigned short* __restrict__ wt,
                                               float* __restrict__ q) {
    __shared__ __align__(16) unsigned short As[32 * 64];
    __shared__ __align__(16) unsigned short Bs[4 * 64 * 64];
    int t = threadIdx.x;
    int w = t >> 6, lane = t & 63;
    int r0 = blockIdx.x * 32;
    int cbase = blockIdx.y * 4;
    {
        int rA = t >> 3, g = t & 7;
        const float* src = h + (size_t)(r0 + rA) * HH + g * 8;
        float4 f0 = *(const float4*)src;
        float4 f1 = *(const float4*)(src + 4);
        us8 v;
        v[0] = f2bf(f0.x); v[1] = f2bf(f0.y); v[2] = f2bf(f0.z); v[3] = f2bf(f0.w);
        v[4] = f2bf(f1.x); v[5] = f2bf(f1.y); v[6] = f2bf(f1.z); v[7] = f2bf(f1.w);
        *(us8*)(As + rA * 64 + ((g ^ (rA & 7)) << 3)) = v;
    }
    {
        const int4* bsrc = (const int4*)(wt + (size_t)(cbase + w) * 4096);
        int4* bdst = (int4*)(Bs + w * 4096);
#pragma unroll
        for (int i = 0; i < 8; i++) bdst[i * 64 + lane] = bsrc[i * 64 + lane];
    }
    __syncthreads();
    f32x4 acc[2][4] = {};
#pragma unroll
    for (int ks = 0; ks < 2; ks++) {
        us8 a0 = ldfrag(As, (lane & 15), ks, lane);
        us8 a1 = ldfrag(As, 16 + (lane & 15), ks, lane);
#pragma unroll
        for (int nf = 0; nf < 4; nf++) {
            us8 b = ldfrag(Bs + w * 4096, nf * 16 + (lane & 15), ks, lane);
            acc[0][nf] = mfma16(a0, b, acc[0][nf]);
            acc[1][nf] = mfma16(a1, b, acc[1][nf]);
        }
    }
#pragma unroll
    for (int mf = 0; mf < 2; mf++) {
#pragma unroll
        for (int reg = 0; reg < 4; reg++) {
            int rt = mf * 16 + ((lane >> 4) << 2) + reg;
            float v = 0.f;
#pragma unroll
            for (int nf = 0; nf < 4; nf++) {
                int k = nf * 16 + (lane & 15);
                float hb = bf2f(As[rt * 64 + (((k >> 3) ^ (rt & 7)) << 3) + (k & 7)]);
                v += acc[mf][nf][reg] * hb;
            }
            v += __shfl_xor(v, 1);
            v += __shfl_xor(v, 2);
            v += __shfl_xor(v, 4);
            v += __shfl_xor(v, 8);
            if ((lane & 15) == 0) q[(size_t)(r0 + rt) * COUT + cbase + w] = v;
        }
    }
}

// ---------------- finalize ----------------
__global__ __launch_bounds__(256) void k_final(const float* __restrict__ h, const float* __restrict__ q,
                                               const float* __restrict__ b1, float* __restrict__ out) {
    int t = threadIdx.x;
    int w = t >> 6, lane = t & 63;
    int r = blockIdx.x * 4 + w;
    float hv = h[(size_t)r * HH + lane];
    float s = hv * hv;
#pragma unroll
    for (int o = 1; o < 64; o <<= 1) s += __shfl_xor(s, o);
    const float maxn = 1.0f - 4e-3f;
    float scale1 = (s > maxn) ? (maxn / s) : 1.f;
    float pn = fmaxf(s * scale1, 1e-15f);
    float tt = atanhf(fminf(pn, 1.f - 1e-7f));
    float gam = (tt / pn) * scale1;
    float z = 0.f;
    if (lane < COUT) z = gam * q[(size_t)r * COUT + lane] + b1[lane];
    float un2 = z * z;
#pragma unroll
    for (int o = 1; o < 64; o <<= 1) un2 += __shfl_xor(un2, o);
    float un = fmaxf(sqrtf(un2), 1e-15f);
    float th = tanhf(un);
    float fac = fminf(th, maxn) / un;
    float f = z * fac;
    float m = (lane < COUT) ? f : -1e30f;
#pragma unroll
    for (int o = 1; o < 64; o <<= 1) m = fmaxf(m, __shfl_xor(m, o));
    float ex = (lane < COUT) ? __expf(f - m) : 0.f;
    float se = ex;
#pragma unroll
    for (int o = 1; o < 64; o <<= 1) se += __shfl_xor(se, o);
    if (lane < COUT) out[(size_t)r * COUT + lane] = f - m - logf(se);
}

extern "C" void kernel_launch(void* const* d_in, const int* in_sizes, int n_in,
                              void* d_out, int out_size, void* d_ws, size_t ws_size,
                              hipStream_t stream) {
    (void)in_sizes; (void)n_in; (void)out_size; (void)ws_size;
    const float* x = (const float*)d_in[0];
    const int* row = (const int*)d_in[1];
    const int* col = (const int*)d_in[2];
    const float* eww = (const float*)d_in[3];
    const float* w0 = (const float*)d_in[4];
    const float* b0 = (const float*)d_in[5];
    const float* convw = (const float*)d_in[6];
    const float* w1 = (const float*)d_in[7];
    const float* b1 = (const float*)d_in[8];
    float* out = (float*)d_out;

    char* ws = (char*)d_ws;
    float* h0 = (float*)(ws + 0);                          // 5,120,000
    float* hA = (float*)(ws + 5120000);                    // 5,120,000
    float* hB = (float*)(ws + 10240000);                   // 5,120,000
    float* q  = (float*)(ws + 15360000);                   // 3,200,000
    int* rs   = (int*)(ws + 18560000);                     // 80,016
    int* cur  = (int*)(ws + 18640016);                     // 80,000
    int2* epk = (int2*)(ws + 18720016);                    // ECAP*8 = 6,400,128
    unsigned short* w0t = (unsigned short*)(ws + 25120144);  // 65,536
    unsigned short* wt  = (unsigned short*)(ws + 25185680);  // 327,680
    float* Wf = (float*)(ws + 25513360);                     // 131,072 -> end ~25.6 MB

    hipMemsetAsync(cur, 0, N_NODES * sizeof(int), stream);
    hipMemsetAsync(epk, 0, (size_t)ECAP * 8, stream);
    k_hist<<<2500, 256, 0, stream>>>(row, cur);
    k_scan<<<1, 1024, 0, stream>>>(cur, rs, cur);
    k_scatter<<<2500, 256, 0, stream>>>(row, col, eww, cur, epk);
    k_w0t<<<128, 256, 0, stream>>>(w0, w0t);
    k_wt<<<640, 256, 0, stream>>>(w1, wt);
    k_wprep<<<128, 256, 0, stream>>>(convw, Wf);
    k_lin0<<<625, 256, 0, stream>>>(x, w0t, b0, h0);

    const float* hp = h0;
    float* hn = hA;
    for (int l = 0; l < NLAYERS; l++) {
        k_layer<<<5000, 256, 0, stream>>>(hp, h0, hn, Wf + l * 4096, rs, epk);
        hp = hn;
        hn = (hn == hA) ? hB : hA;
    }
    k_qform<<<dim3(625, 10), 256, 0, stream>>>(hp, wt, q);
    k_final<<<5000, 256, 0, stream>>>(hp, q, b1, out);
}

// Round 6
// 427.565 us; speedup vs baseline: 1.5366x; 1.0028x over previous
//
#include <hip/hip_runtime.h>
#include <hip/hip_bf16.h>
#include <math.h>

#define N_NODES 20000
#define F_INN 512
#define HH 64
#define NLAYERS 8
#define E_EDGES 640000
#define COUT 40
#define ECAP 800016   // padded CSR capacity: sum ceil(deg/8)*8 <= E + 7*N = 780000

typedef __bf16 bf16x8 __attribute__((ext_vector_type(8)));
typedef float f32x4 __attribute__((ext_vector_type(4)));
typedef unsigned short us8 __attribute__((ext_vector_type(8)));

__device__ __forceinline__ unsigned short f2bf(float f) {
    unsigned int u = __builtin_bit_cast(unsigned int, f);
    u += 0x7FFFu + ((u >> 16) & 1u);   // RNE
    return (unsigned short)(u >> 16);
}
__device__ __forceinline__ float bf2f(unsigned short s) {
    unsigned int u = ((unsigned int)s) << 16;
    return __builtin_bit_cast(float, u);
}
__device__ __forceinline__ float i2f(int s) { return __builtin_bit_cast(float, s); }

// Swizzled-tile fragment load (MFMA 16x16x32 bf16). Tile [rows][64k] bf16,
// element (r,k) at r*64 + ((k>>3)^(r&7))*8 + (k&7).
__device__ __forceinline__ us8 ldfrag(const unsigned short* tile, int row, int ks, int lane) {
    int slot = ks * 4 + (lane >> 4);
    int off = row * 64 + ((slot ^ (row & 7)) << 3);
    return *(const us8*)(tile + off);
}

__device__ __forceinline__ f32x4 mfma16(us8 a, us8 b, f32x4 c) {
    return __builtin_amdgcn_mfma_f32_16x16x32_bf16(
        __builtin_bit_cast(bf16x8, a), __builtin_bit_cast(bf16x8, b), c, 0, 0, 0);
}

// ---------------- CSR build ----------------
__global__ __launch_bounds__(256) void k_hist(const int* __restrict__ row, int* __restrict__ cnt) {
    int e = blockIdx.x * 256 + threadIdx.x;
    if (e < E_EDGES) atomicAdd(&cnt[row[e]], 1);
}

__global__ __launch_bounds__(1024) void k_scan(const int* __restrict__ cnt, int* __restrict__ row_start,
                                               int* __restrict__ cursor) {
    __shared__ int sd[1024];
    int t = threadIdx.x;
    int local[20];
    int s = 0;
    int base = t * 20;
#pragma unroll
    for (int i = 0; i < 20; i++) {
        int idx = base + i;
        int v = (idx < N_NODES) ? ((cnt[idx] + 7) & ~7) : 0;   // pad rows to x8
        local[i] = v; s += v;
    }
    sd[t] = s;
    __syncthreads();
    for (int d = 1; d < 1024; d <<= 1) {
        int v = (t >= d) ? sd[t - d] : 0;
        __syncthreads();
        sd[t] += v;
        __syncthreads();
    }
    int run = sd[t] - s;
#pragma unroll
    for (int i = 0; i < 20; i++) {
        int idx = base + i;
        if (idx < N_NODES) { row_start[idx] = run; cursor[idx] = run; run += local[i]; }
    }
    if (t == 1023) row_start[N_NODES] = sd[1023];
}

__global__ __launch_bounds__(256) void k_scatter(const int* __restrict__ row, const int* __restrict__ col,
                                                 const float* __restrict__ ewin, int* __restrict__ cursor,
                                                 int2* __restrict__ epk) {
    int e = blockIdx.x * 256 + threadIdx.x;
    if (e < E_EDGES) {
        int r = row[e];
        int p = atomicAdd(&cursor[r], 1);
        int2 v;
        v.x = col[e];
        v.y = __builtin_bit_cast(int, ewin[e]);
        epk[p] = v;
    }
}

// ---------------- weight prep ----------------
__global__ __launch_bounds__(256) void k_w0t(const float* __restrict__ w0, unsigned short* __restrict__ w0t) {
    int idx = blockIdx.x * 256 + threadIdx.x;  // 32768
    if (idx < F_INN * HH) {
        int k = idx >> 6, f = idx & 63;
        w0t[f * 512 + (((k >> 3) ^ (f & 7)) << 3) + (k & 7)] = f2bf(w0[idx]);
    }
}
__global__ __launch_bounds__(256) void k_wt(const float* __restrict__ w1, unsigned short* __restrict__ wt) {
    int idx = blockIdx.x * 256 + threadIdx.x;  // 163840
    if (idx < HH * HH * COUT) {
        int klin = idx / 40;
        int c = idx - klin * 40;
        int i = klin >> 6, j = klin & 63;
        wt[c * 4096 + i * 64 + (((j >> 3) ^ (i & 7)) << 3) + (j & 7)] = f2bf(w1[idx]);
    }
}
// Wf[l][k][c] = beta_l*conv_w[l][k][c] + (k==c)*(1-beta_l), f32 (no transpose)
__global__ __launch_bounds__(256) void k_wprep(const float* __restrict__ convw, float* __restrict__ Wf) {
    int idx = blockIdx.x * 256 + threadIdx.x;  // 8*4096
    if (idx < NLAYERS * HH * HH) {
        int l = idx >> 12;
        int k = (idx >> 6) & 63, c = idx & 63;
        float beta = logf(0.5f / (float)(l + 1) + 1.0f);
        Wf[idx] = beta * convw[idx] + ((k == c) ? (1.0f - beta) : 0.0f);
    }
}

// ---------------- lin0: h0 = relu(x @ W0 + b0), MFMA bf16, bf16 out ----------------
__global__ __launch_bounds__(256) void k_lin0(const float* __restrict__ x, const unsigned short* __restrict__ w0t,
                                              const float* __restrict__ b0, unsigned short* __restrict__ h0b) {
    __shared__ __align__(16) unsigned short As[32 * 64];
    __shared__ __align__(16) unsigned short Bs[64 * 64];
    const int t = threadIdx.x;
    const int w = t >> 6, lane = t & 63;
    const int r0 = blockIdx.x * 32;
    const int rA = t >> 3, g = t & 7;
    f32x4 acc[2] = {};
    for (int kc = 0; kc < 8; kc++) {
        if (kc) __syncthreads();
        {
            const float* src = x + (size_t)(r0 + rA) * F_INN + kc * 64 + g * 8;
            float4 f0 = *(const float4*)src;
            float4 f1 = *(const float4*)(src + 4);
            us8 v;
            v[0] = f2bf(f0.x); v[1] = f2bf(f0.y); v[2] = f2bf(f0.z); v[3] = f2bf(f0.w);
            v[4] = f2bf(f1.x); v[5] = f2bf(f1.y); v[6] = f2bf(f1.z); v[7] = f2bf(f1.w);
            *(us8*)(As + rA * 64 + ((g ^ (rA & 7)) << 3)) = v;
        }
        {
            const int4* bsrc = (const int4*)w0t;
            int4* bdst = (int4*)Bs;
#pragma unroll
            for (int i = 0; i < 2; i++) {
                int flat = t * 2 + i;
                int f = flat >> 3, u = flat & 7;
                bdst[f * 8 + u] = bsrc[f * 64 + kc * 8 + u];
            }
        }
        __syncthreads();
#pragma unroll
        for (int ks = 0; ks < 2; ks++) {
            us8 b = ldfrag(Bs, w * 16 + (lane & 15), ks, lane);
            us8 a0 = ldfrag(As, (lane & 15), ks, lane);
            us8 a1 = ldfrag(As, 16 + (lane & 15), ks, lane);
            acc[0] = mfma16(a0, b, acc[0]);
            acc[1] = mfma16(a1, b, acc[1]);
        }
    }
    const int colc = w * 16 + (lane & 15);
    float bias = b0[colc];
#pragma unroll
    for (int mf = 0; mf < 2; mf++) {
#pragma unroll
        for (int reg = 0; reg < 4; reg++) {
            int rowg = r0 + mf * 16 + ((lane >> 4) << 2) + reg;
            h0b[(size_t)rowg * HH + colc] = f2bf(fmaxf(acc[mf][reg] + bias, 0.f));
        }
    }
}

// ---------------- fused layer: bf16 gather-spmm + residual + matvec(W') + relu ----------------
__global__ __launch_bounds__(256) void k_layer(const unsigned short* __restrict__ hp,
                                               const unsigned short* __restrict__ h0,
                                               unsigned short* __restrict__ hn, const float* __restrict__ W,
                                               const int* __restrict__ rs, const int2* __restrict__ epk) {
    __shared__ float Wl[4096];
    __shared__ float rowbuf[4][64];
    const int t = threadIdx.x;
#pragma unroll
    for (int i = 0; i < 16; i++) Wl[t + i * 256] = W[t + i * 256];
    __syncthreads();
    const int w = t >> 6, lane = t & 63;
    const int r = blockIdx.x * 4 + w;
    const int e0 = rs[r], e1 = rs[r + 1];
    float acc = 0.f;
    int e = e0;
    if (e < e1) {
        int4 a = *(const int4*)(epk + e);
        int4 b = *(const int4*)(epk + e + 2);
        int4 c = *(const int4*)(epk + e + 4);
        int4 d = *(const int4*)(epk + e + 6);
        for (;;) {
            int4 A = a, B = b, C = c, D = d;
            int en = e + 8;
            bool more = en < e1;
            if (more) {
                a = *(const int4*)(epk + en);
                b = *(const int4*)(epk + en + 2);
                c = *(const int4*)(epk + en + 4);
                d = *(const int4*)(epk + en + 6);
            }
            acc += i2f(A.y) * bf2f(hp[(size_t)A.x * HH + lane]);
            acc += i2f(A.w) * bf2f(hp[(size_t)A.z * HH + lane]);
            acc += i2f(B.y) * bf2f(hp[(size_t)B.x * HH + lane]);
            acc += i2f(B.w) * bf2f(hp[(size_t)B.z * HH + lane]);
            acc += i2f(C.y) * bf2f(hp[(size_t)C.x * HH + lane]);
            acc += i2f(C.w) * bf2f(hp[(size_t)C.z * HH + lane]);
            acc += i2f(D.y) * bf2f(hp[(size_t)D.x * HH + lane]);
            acc += i2f(D.w) * bf2f(hp[(size_t)D.z * HH + lane]);
            if (!more) break;
            e = en;
        }
    }
    float outv = 0.9f * acc + 0.1f * bf2f(h0[(size_t)r * HH + lane]);
    rowbuf[w][lane] = outv;
    float tmp = 0.f;
    const float* rb = rowbuf[w];
#pragma unroll
    for (int k = 0; k < 64; k += 4) {
        float4 o = *(const float4*)(rb + k);
        tmp += o.x * Wl[(k + 0) * 64 + lane];
        tmp += o.y * Wl[(k + 1) * 64 + lane];
        tmp += o.z * Wl[(k + 2) * 64 + lane];
        tmp += o.w * Wl[(k + 3) * 64 + lane];
    }
    hn[(size_t)r * HH + lane] = f2bf(fmaxf(tmp, 0.f));
}

// ---------------- final quadratic form: q[n,c] = h^T M_c h via MFMA ----------------
__global__ __launch_bounds__(256) void k_qform(const unsigned short* __restrict__ hb,
                                               const unsigned short* __restrict__ wt,
                                               float* __restrict__ q) {
    __shared__ __align__(16) unsigned short As[32 * 64];
    __shared__ __align__(16) unsigned short Bs[4 * 64 * 64];
    int t = threadIdx.x;
    int w = t >> 6, lane = t & 63;
    int r0 = blockIdx.x * 32;
    int cbase = blockIdx.y * 4;
    {   // stage A: h tile [32 x 64] bf16, swizzle (straight 16B copies)
        int rA = t >> 3, g = t & 7;
        us8 v = *(const us8*)(hb + (size_t)(r0 + rA) * HH + g * 8);
        *(us8*)(As + rA * 64 + ((g ^ (rA & 7)) << 3)) = v;
    }
    {
        const int4* bsrc = (const int4*)(wt + (size_t)(cbase + w) * 4096);
        int4* bdst = (int4*)(Bs + w * 4096);
#pragma unroll
        for (int i = 0; i < 8; i++) bdst[i * 64 + lane] = bsrc[i * 64 + lane];
    }
    __syncthreads();
    f32x4 acc[2][4] = {};
#pragma unroll
    for (int ks = 0; ks < 2; ks++) {
        us8 a0 = ldfrag(As, (lane & 15), ks, lane);
        us8 a1 = ldfrag(As, 16 + (lane & 15), ks, lane);
#pragma unroll
        for (int nf = 0; nf < 4; nf++) {
            us8 b = ldfrag(Bs + w * 4096, nf * 16 + (lane & 15), ks, lane);
            acc[0][nf] = mfma16(a0, b, acc[0][nf]);
            acc[1][nf] = mfma16(a1, b, acc[1][nf]);
        }
    }
#pragma unroll
    for (int mf = 0; mf < 2; mf++) {
#pragma unroll
        for (int reg = 0; reg < 4; reg++) {
            int rt = mf * 16 + ((lane >> 4) << 2) + reg;
            float v = 0.f;
#pragma unroll
            for (int nf = 0; nf < 4; nf++) {
                int k = nf * 16 + (lane & 15);
                float hb2 = bf2f(As[rt * 64 + (((k >> 3) ^ (rt & 7)) << 3) + (k & 7)]);
                v += acc[mf][nf][reg] * hb2;
            }
            v += __shfl_xor(v, 1);
            v += __shfl_xor(v, 2);
            v += __shfl_xor(v, 4);
            v += __shfl_xor(v, 8);
            if ((lane & 15) == 0) q[(size_t)(r0 + rt) * COUT + cbase + w] = v;
        }
    }
}

// ---------------- finalize ----------------
__global__ __launch_bounds__(256) void k_final(const unsigned short* __restrict__ hb, const float* __restrict__ q,
                                               const float* __restrict__ b1, float* __restrict__ out) {
    int t = threadIdx.x;
    int w = t >> 6, lane = t & 63;
    int r = blockIdx.x * 4 + w;
    float hv = bf2f(hb[(size_t)r * HH + lane]);
    float s = hv * hv;
#pragma unroll
    for (int o = 1; o < 64; o <<= 1) s += __shfl_xor(s, o);
    const float maxn = 1.0f - 4e-3f;
    float scale1 = (s > maxn) ? (maxn / s) : 1.f;
    float pn = fmaxf(s * scale1, 1e-15f);
    float tt = atanhf(fminf(pn, 1.f - 1e-7f));
    float gam = (tt / pn) * scale1;
    float z = 0.f;
    if (lane < COUT) z = gam * q[(size_t)r * COUT + lane] + b1[lane];
    float un2 = z * z;
#pragma unroll
    for (int o = 1; o < 64; o <<= 1) un2 += __shfl_xor(un2, o);
    float un = fmaxf(sqrtf(un2), 1e-15f);
    float th = tanhf(un);
    float fac = fminf(th, maxn) / un;
    float f = z * fac;
    float m = (lane < COUT) ? f : -1e30f;
#pragma unroll
    for (int o = 1; o < 64; o <<= 1) m = fmaxf(m, __shfl_xor(m, o));
    float ex = (lane < COUT) ? __expf(f - m) : 0.f;
    float se = ex;
#pragma unroll
    for (int o = 1; o < 64; o <<= 1) se += __shfl_xor(se, o);
    if (lane < COUT) out[(size_t)r * COUT + lane] = f - m - logf(se);
}

extern "C" void kernel_launch(void* const* d_in, const int* in_sizes, int n_in,
                              void* d_out, int out_size, void* d_ws, size_t ws_size,
                              hipStream_t stream) {
    (void)in_sizes; (void)n_in; (void)out_size; (void)ws_size;
    const float* x = (const float*)d_in[0];
    const int* row = (const int*)d_in[1];
    const int* col = (const int*)d_in[2];
    const float* eww = (const float*)d_in[3];
    const float* w0 = (const float*)d_in[4];
    const float* b0 = (const float*)d_in[5];
    const float* convw = (const float*)d_in[6];
    const float* w1 = (const float*)d_in[7];
    const float* b1 = (const float*)d_in[8];
    float* out = (float*)d_out;

    char* ws = (char*)d_ws;
    unsigned short* h0b = (unsigned short*)(ws + 0);        // 2,560,000
    unsigned short* hAb = (unsigned short*)(ws + 2560000);  // 2,560,000
    unsigned short* hBb = (unsigned short*)(ws + 5120000);  // 2,560,000
    float* q  = (float*)(ws + 7680000);                     // 3,200,000
    int* rs   = (int*)(ws + 10880000);                      // 80,016
    int* cur  = (int*)(ws + 10960016);                      // 80,000
    int2* epk = (int2*)(ws + 11040016);                     // ECAP*8 = 6,400,128
    unsigned short* w0t = (unsigned short*)(ws + 17440144);  // 65,536
    unsigned short* wt  = (unsigned short*)(ws + 17505680);  // 327,680
    float* Wf = (float*)(ws + 17833360);                     // 131,072 -> end ~18.0 MB

    hipMemsetAsync(cur, 0, N_NODES * sizeof(int), stream);
    hipMemsetAsync(epk, 0, (size_t)ECAP * 8, stream);
    k_hist<<<2500, 256, 0, stream>>>(row, cur);
    k_scan<<<1, 1024, 0, stream>>>(cur, rs, cur);
    k_scatter<<<2500, 256, 0, stream>>>(row, col, eww, cur, epk);
    k_w0t<<<128, 256, 0, stream>>>(w0, w0t);
    k_wt<<<640, 256, 0, stream>>>(w1, wt);
    k_wprep<<<128, 256, 0, stream>>>(convw, Wf);
    k_lin0<<<625, 256, 0, stream>>>(x, w0t, b0, h0b);

    const unsigned short* hp = h0b;
    unsigned short* hn = hAb;
    for (int l = 0; l < NLAYERS; l++) {
        k_layer<<<5000, 256, 0, stream>>>(hp, h0b, hn, Wf + l * 4096, rs, epk);
        hp = hn;
        hn = (hn == hAb) ? hBb : hAb;
    }
    k_qform<<<dim3(625, 10), 256, 0, stream>>>(hp, wt, q);
    k_final<<<5000, 256, 0, stream>>>(hp, q, b1, out);
}